// Round 4
// baseline (67.372 us; speedup 1.0000x reference)
//
#include <hip/hip_runtime.h>
#include <hip/hip_bf16.h>

// FAVOR+ bidirectional linear attention, N=262144, D=64, fp32 in/out.
// Pass 1 (barrier-free inner loop): K/V projections (bf16 MFMA); kv accumulated
//   per-wave in registers using the projection C-layout directly as kv MFMA
//   operands (contraction re-ordered over tile pairs); wave partials merged in
//   LDS once at the end -> per-block partial kv/ksum.
// Reduce: sum 512 block partials -> kv[64][64], ksum[64].
// Pass 2 (barrier-free inner loop): Q projection -> qp; wave-private LDS
//   transpose (double-buffered, lgkmcnt-only sync) -> num = qp@kv; denom via
//   butterfly; out = num/denom.

#define NPTS 262144
#define TILES (NPTS / 64)      // 4096
#define GRID1 512
#define TPB1 (TILES / GRID1)   // 8 tiles = 4 pairs
#define PAIRS1 (TPB1 / 2)
#define GRID2 1024
#define TPB2 (TILES / GRID2)   // 4
#define EPS 1e-3f

typedef __attribute__((ext_vector_type(8))) short short8;   // 8 x bf16 (4 VGPRs)
typedef __attribute__((ext_vector_type(4))) float f32x4;

__device__ __forceinline__ unsigned short f2bf(float f) {
    unsigned u = __builtin_bit_cast(unsigned, f);
    u += 0x7FFFu + ((u >> 16) & 1u);           // round-to-nearest-even
    return (unsigned short)(u >> 16);
}

// B-fragment gather from global f32 row-major [64][64]: lane holds B[k][col], k = kk*32 + lg*8 + e
__device__ __forceinline__ short8 load_bfrag(const float* __restrict__ W, int kk, int lg, int col) {
    short8 t;
    const float* p = W + (size_t)(kk * 32 + lg * 8) * 64 + col;
#pragma unroll
    for (int e = 0; e < 8; ++e) t[e] = (short)f2bf(p[(size_t)e * 64]);
    return t;
}

__device__ __forceinline__ short8 cvt8(float4 p0, float4 p1) {
    short8 a;
    a[0] = (short)f2bf(p0.x); a[1] = (short)f2bf(p0.y); a[2] = (short)f2bf(p0.z); a[3] = (short)f2bf(p0.w);
    a[4] = (short)f2bf(p1.x); a[5] = (short)f2bf(p1.y); a[6] = (short)f2bf(p1.z); a[7] = (short)f2bf(p1.w);
    return a;
}

// barrier that drains LDS ops only (keeps global prefetch loads in flight)
__device__ __forceinline__ void lds_barrier() {
    asm volatile("s_waitcnt lgkmcnt(0)" ::: "memory");
    __builtin_amdgcn_s_barrier();
}
__device__ __forceinline__ void lds_drain() {
    asm volatile("s_waitcnt lgkmcnt(0)" ::: "memory");
}

__global__ __launch_bounds__(256, 2) void pass1_kernel(
    const float* __restrict__ x, const float* __restrict__ Wk, const float* __restrict__ bk,
    const float* __restrict__ Wv, const float* __restrict__ bv,
    float* __restrict__ kvPart, float* __restrict__ ksPart)
{
    __shared__ unsigned short wkF[8][64][8];     // Wk B-frags: [j*2+kk][lane][e]
    __shared__ unsigned short wvF[8][64][8];     // Wv B-frags
    __shared__ float redA[4096];                 // end-of-kernel wave merge
    __shared__ float redB[4096];

    const int tid = threadIdx.x;
    const int w = tid >> 6, l = tid & 63, l15 = l & 15, lg = l >> 4;

    // build weight frags once per block (each wave builds 4 of the 16 entries)
    {
        const float* W = (w < 2) ? Wk : Wv;
        int jbase = (w & 1) * 2;
#pragma unroll
        for (int jj = 0; jj < 2; ++jj)
#pragma unroll
            for (int kk = 0; kk < 2; ++kk) {
                short8 f = load_bfrag(W, kk, lg, (jbase + jj) * 16 + l15);
                if (w < 2) *(short8*)&wkF[(jbase + jj) * 2 + kk][l][0] = f;
                else       *(short8*)&wvF[(jbase + jj) * 2 + kk][l][0] = f;
            }
    }
    float bkl[4], bvl[4];
#pragma unroll
    for (int j = 0; j < 4; ++j) { bkl[j] = bk[j * 16 + l15]; bvl[j] = bv[j * 16 + l15]; }

    f32x4 akv[4][4];    // [jm][jd]: kv[jm*16+lg*4+r][jd*16+l15], wave-partial
#pragma unroll
    for (int jm = 0; jm < 4; ++jm)
#pragma unroll
        for (int jd = 0; jd < 4; ++jd) akv[jm][jd] = (f32x4){0.f, 0.f, 0.f, 0.f};
    float ks[4] = {0.f, 0.f, 0.f, 0.f};

    lds_barrier();   // weight frags ready (only cross-wave sync until the end)

    const int t0 = blockIdx.x * TPB1;
    const float* xbase = x + ((size_t)t0 * 64 + w * 16 + l15) * 64 + lg * 8;
    float4 cA0 = *(const float4*)(xbase + 0);
    float4 cA1 = *(const float4*)(xbase + 4);
    float4 cA2 = *(const float4*)(xbase + 32);
    float4 cA3 = *(const float4*)(xbase + 36);
    float4 cB0 = *(const float4*)(xbase + 4096 + 0);
    float4 cB1 = *(const float4*)(xbase + 4096 + 4);
    float4 cB2 = *(const float4*)(xbase + 4096 + 32);
    float4 cB3 = *(const float4*)(xbase + 4096 + 36);

#pragma unroll
    for (int p = 0; p < PAIRS1; ++p) {
        // prefetch next pair (safe re-read of current on last iter)
        const float* xn = xbase + (size_t)((p + 1 < PAIRS1) ? (p + 1) : p) * 8192;
        float4 nA0 = *(const float4*)(xn + 0);
        float4 nA1 = *(const float4*)(xn + 4);
        float4 nA2 = *(const float4*)(xn + 32);
        float4 nA3 = *(const float4*)(xn + 36);
        float4 nB0 = *(const float4*)(xn + 4096 + 0);
        float4 nB1 = *(const float4*)(xn + 4096 + 4);
        float4 nB2 = *(const float4*)(xn + 4096 + 32);
        float4 nB3 = *(const float4*)(xn + 4096 + 36);

        short8 a0A = cvt8(cA0, cA1), a1A = cvt8(cA2, cA3);
        short8 a0B = cvt8(cB0, cB1), a1B = cvt8(cB2, cB3);

        short8 kpc[4], vc[4];   // combined pair fragments for kv MFMA
#pragma unroll
        for (int j = 0; j < 4; ++j) {
            short8 bk0 = *(const short8*)&wkF[j * 2 + 0][l][0];
            short8 bk1 = *(const short8*)&wkF[j * 2 + 1][l][0];
            short8 bv0 = *(const short8*)&wvF[j * 2 + 0][l][0];
            short8 bv1 = *(const short8*)&wvF[j * 2 + 1][l][0];
            f32x4 z = (f32x4){0.f, 0.f, 0.f, 0.f};
            f32x4 akA = __builtin_amdgcn_mfma_f32_16x16x32_bf16(a0A, bk0, z, 0, 0, 0);
            akA = __builtin_amdgcn_mfma_f32_16x16x32_bf16(a1A, bk1, akA, 0, 0, 0);
            f32x4 avA = __builtin_amdgcn_mfma_f32_16x16x32_bf16(a0A, bv0, z, 0, 0, 0);
            avA = __builtin_amdgcn_mfma_f32_16x16x32_bf16(a1A, bv1, avA, 0, 0, 0);
            f32x4 akB = __builtin_amdgcn_mfma_f32_16x16x32_bf16(a0B, bk0, z, 0, 0, 0);
            akB = __builtin_amdgcn_mfma_f32_16x16x32_bf16(a1B, bk1, akB, 0, 0, 0);
            f32x4 avB = __builtin_amdgcn_mfma_f32_16x16x32_bf16(a0B, bv0, z, 0, 0, 0);
            avB = __builtin_amdgcn_mfma_f32_16x16x32_bf16(a1B, bv1, avB, 0, 0, 0);
            short8 kc, vv;
#pragma unroll
            for (int r = 0; r < 4; ++r) {
                float kA = fmaxf(akA[r] + bkl[j], 0.f) + EPS;
                float kB = fmaxf(akB[r] + bkl[j], 0.f) + EPS;
                ks[j] += kA + kB;
                kc[r] = (short)f2bf(kA);
                kc[4 + r] = (short)f2bf(kB);
                vv[r] = (short)f2bf(avA[r] + bvl[j]);
                vv[4 + r] = (short)f2bf(avB[r] + bvl[j]);
            }
            kpc[j] = kc; vc[j] = vv;
        }
        // kv[m][d] += kp^T v over this pair's 32 rows; contraction k = lg*8 + tile*4 + r
#pragma unroll
        for (int jm = 0; jm < 4; ++jm)
#pragma unroll
            for (int jd = 0; jd < 4; ++jd)
                akv[jm][jd] = __builtin_amdgcn_mfma_f32_16x16x32_bf16(kpc[jm], vc[jd], akv[jm][jd], 0, 0, 0);

        cA0 = nA0; cA1 = nA1; cA2 = nA2; cA3 = nA3;
        cB0 = nB0; cB1 = nB1; cB2 = nB2; cB3 = nB3;
    }

    // merge the 4 wave partials in LDS: w1->redA, w3->redB; w0+=redA, w2+=redB; w2->redA; w0 stores
#define KV_IDX(jm, jd, r) ((size_t)((jm) * 16 + lg * 4 + (r)) * 64 + (jd) * 16 + l15)
    if (w == 1 || w == 3) {
        float* dst = (w == 1) ? redA : redB;
#pragma unroll
        for (int jm = 0; jm < 4; ++jm)
#pragma unroll
            for (int jd = 0; jd < 4; ++jd)
#pragma unroll
                for (int r = 0; r < 4; ++r) dst[KV_IDX(jm, jd, r)] = akv[jm][jd][r];
    }
    __syncthreads();
    if (w == 0 || w == 2) {
        const float* src = (w == 0) ? redA : redB;
#pragma unroll
        for (int jm = 0; jm < 4; ++jm)
#pragma unroll
            for (int jd = 0; jd < 4; ++jd)
#pragma unroll
                for (int r = 0; r < 4; ++r) akv[jm][jd][r] += src[KV_IDX(jm, jd, r)];
    }
    __syncthreads();
    if (w == 2) {
#pragma unroll
        for (int jm = 0; jm < 4; ++jm)
#pragma unroll
            for (int jd = 0; jd < 4; ++jd)
#pragma unroll
                for (int r = 0; r < 4; ++r) redA[KV_IDX(jm, jd, r)] = akv[jm][jd][r];
    }
    __syncthreads();
    if (w == 0) {
        float* kvs = kvPart + (size_t)blockIdx.x * 4096;
#pragma unroll
        for (int jm = 0; jm < 4; ++jm)
#pragma unroll
            for (int jd = 0; jd < 4; ++jd)
#pragma unroll
                for (int r = 0; r < 4; ++r)
                    kvs[KV_IDX(jm, jd, r)] = akv[jm][jd][r] + redA[KV_IDX(jm, jd, r)];
    }
#undef KV_IDX
    // ksum partial per (block, wave)
#pragma unroll
    for (int j = 0; j < 4; ++j) {
        float s = ks[j];
        s += __shfl_xor(s, 16, 64);
        s += __shfl_xor(s, 32, 64);
        if (lg == 0) ksPart[(size_t)blockIdx.x * 256 + w * 64 + j * 16 + l15] = s;
    }
}

// 65 blocks: b<64 -> kv outputs b*64..b*64+63; b==64 -> ksum outputs 0..63
__global__ __launch_bounds__(256, 4) void reduce_kernel(
    const float* __restrict__ kvPart, const float* __restrict__ ksPart,
    float* __restrict__ kvFin, float* __restrict__ ksFin)
{
    __shared__ float red[4][64];
    const int b = blockIdx.x, t = threadIdx.x;
    const int oo = t & 63, sc = t >> 6;
    float acc = 0.f;
    if (b < 64) {
        const float* p = kvPart + (size_t)sc * 128 * 4096 + b * 64 + oo;
#pragma unroll 8
        for (int s = 0; s < GRID1 / 4; ++s) acc += p[(size_t)s * 4096];
    } else {
        const float* p = ksPart + (size_t)sc * (GRID1) * 64 + oo;
#pragma unroll 8
        for (int s = 0; s < GRID1; ++s) acc += p[(size_t)s * 64];
    }
    red[sc][oo] = acc;
    __syncthreads();
    if (t < 64) {
        float s = red[0][t] + red[1][t] + red[2][t] + red[3][t];
        if (b < 64) kvFin[b * 64 + t] = s;
        else        ksFin[t] = s;
    }
}

__global__ __launch_bounds__(256, 4) void pass2_kernel(
    const float* __restrict__ x, const float* __restrict__ Wq, const float* __restrict__ bq,
    const float* __restrict__ kvFin, const float* __restrict__ ksFin,
    float* __restrict__ out)
{
    __shared__ unsigned short qpS[2][64][72];  // wave-private qp staging, double-buffered
    __shared__ unsigned short wqF[8][64][8];   // Wq B-frags
    __shared__ unsigned short kvF[8][64][8];   // kv B-frags

    const int tid = threadIdx.x;
    const int w = tid >> 6, l = tid & 63, l15 = l & 15, lg = l >> 4;

    // weight + kv frags from global (wave w builds j = w)
#pragma unroll
    for (int kk = 0; kk < 2; ++kk) {
        short8 f = load_bfrag(Wq, kk, lg, w * 16 + l15);
        *(short8*)&wqF[w * 2 + kk][l][0] = f;
        short8 g = load_bfrag(kvFin, kk, lg, w * 16 + l15);
        *(short8*)&kvF[w * 2 + kk][l][0] = g;
    }
    float bql[4], ksl[4];
#pragma unroll
    for (int j = 0; j < 4; ++j) { bql[j] = bq[j * 16 + l15]; ksl[j] = ksFin[j * 16 + l15]; }

    lds_barrier();   // frags ready — the only block-wide barrier

    const int t0 = blockIdx.x * TPB2;
    const float* xbase = x + ((size_t)t0 * 64 + w * 16 + l15) * 64 + lg * 8;
    float4 c0 = *(const float4*)(xbase + 0);
    float4 c1 = *(const float4*)(xbase + 4);
    float4 c2 = *(const float4*)(xbase + 32);
    float4 c3 = *(const float4*)(xbase + 36);

#pragma unroll
    for (int t = 0; t < TPB2; ++t) {
        const float* xn = xbase + (size_t)((t + 1 < TPB2) ? (t + 1) : t) * 4096;
        float4 n0 = *(const float4*)(xn + 0);
        float4 n1 = *(const float4*)(xn + 4);
        float4 n2 = *(const float4*)(xn + 32);
        float4 n3 = *(const float4*)(xn + 36);

        short8 a0 = cvt8(c0, c1);
        short8 a1 = cvt8(c2, c3);

        float qp[4][4];
#pragma unroll
        for (int j = 0; j < 4; ++j) {
            short8 bq0 = *(const short8*)&wqF[j * 2 + 0][l][0];
            short8 bq1 = *(const short8*)&wqF[j * 2 + 1][l][0];
            f32x4 z = (f32x4){0.f, 0.f, 0.f, 0.f};
            f32x4 aq = __builtin_amdgcn_mfma_f32_16x16x32_bf16(a0, bq0, z, 0, 0, 0);
            aq = __builtin_amdgcn_mfma_f32_16x16x32_bf16(a1, bq1, aq, 0, 0, 0);
#pragma unroll
            for (int r = 0; r < 4; ++r) qp[j][r] = fmaxf(aq[r] + bql[j], 0.f) + EPS;
        }
        // denom[row] = sum_m qp[row][m]*ksum[m]; butterfly across the 16 col-lanes
        float dp[4];
#pragma unroll
        for (int r = 0; r < 4; ++r)
            dp[r] = qp[0][r] * ksl[0] + qp[1][r] * ksl[1] + qp[2][r] * ksl[2] + qp[3][r] * ksl[3];
#pragma unroll
        for (int mask = 1; mask <= 8; mask <<= 1)
#pragma unroll
            for (int r = 0; r < 4; ++r) dp[r] += __shfl_xor(dp[r], mask, 64);

        // wave-private transpose: wave w writes rows w*16..w*16+15 and reads them back
        const int buf = t & 1;
        const int nb = w * 16 + lg * 4;
#pragma unroll
        for (int j = 0; j < 4; ++j)
#pragma unroll
            for (int r = 0; r < 4; ++r)
                qpS[buf][nb + r][j * 16 + l15] = f2bf(qp[j][r]);
        lds_drain();   // wave's own writes visible; no cross-wave dependency

        short8 an0 = *(const short8*)&qpS[buf][w * 16 + l15][lg * 8];
        short8 an1 = *(const short8*)&qpS[buf][w * 16 + l15][32 + lg * 8];
        float inv[4];
#pragma unroll
        for (int r = 0; r < 4; ++r) inv[r] = __builtin_amdgcn_rcpf(dp[r]);
        const int row0 = (t0 + t) * 64 + w * 16;
#pragma unroll
        for (int j = 0; j < 4; ++j) {
            short8 kv0 = *(const short8*)&kvF[j * 2 + 0][l][0];
            short8 kv1 = *(const short8*)&kvF[j * 2 + 1][l][0];
            f32x4 z = (f32x4){0.f, 0.f, 0.f, 0.f};
            f32x4 nm = __builtin_amdgcn_mfma_f32_16x16x32_bf16(an0, kv0, z, 0, 0, 0);
            nm = __builtin_amdgcn_mfma_f32_16x16x32_bf16(an1, kv1, nm, 0, 0, 0);
#pragma unroll
            for (int r = 0; r < 4; ++r)
                out[(size_t)(row0 + lg * 4 + r) * 64 + j * 16 + l15] = nm[r] * inv[r];
        }
        c0 = n0; c1 = n1; c2 = n2; c3 = n3;
    }
}

extern "C" void kernel_launch(void* const* d_in, const int* in_sizes, int n_in,
                              void* d_out, int out_size, void* d_ws, size_t ws_size,
                              hipStream_t stream)
{
    const float* x  = (const float*)d_in[0];
    const float* Wq = (const float*)d_in[1];
    const float* bq = (const float*)d_in[2];
    const float* Wk = (const float*)d_in[3];
    const float* bk = (const float*)d_in[4];
    const float* Wv = (const float*)d_in[5];
    const float* bv = (const float*)d_in[6];
    float* out = (float*)d_out;

    float* kvPart = (float*)d_ws;                              // [512][4096]
    float* ksPart = kvPart + (size_t)GRID1 * 4096;             // [512][4][64]
    float* kvFin  = ksPart + (size_t)GRID1 * 256;              // [4096]
    float* ksFin  = kvFin + 4096;                              // [64]

    hipLaunchKernelGGL(pass1_kernel, dim3(GRID1), dim3(256), 0, stream,
                       x, Wk, bk, Wv, bv, kvPart, ksPart);
    hipLaunchKernelGGL(reduce_kernel, dim3(65), dim3(256), 0, stream,
                       kvPart, ksPart, kvFin, ksFin);
    hipLaunchKernelGGL(pass2_kernel, dim3(GRID2), dim3(256), 0, stream,
                       x, Wq, bq, kvFin, ksFin, out);
}

// Round 5
// 64.611 us; speedup vs baseline: 1.0427x; 1.0427x over previous
//
#include <hip/hip_runtime.h>
#include <hip/hip_bf16.h>

// FAVOR+ bidirectional linear attention, N=262144, D=64, fp32 in/out.
// Pass 1: K/V/Q projections (bf16 MFMA, weights staged coalesced->LDS frags);
//   kv via LDS-transpose + MFMA accumulate -> per-block partials (plain stores);
//   qp exported to ws as bf16 rows (pass2 A-frags load directly).
// Reduce: sum 512 block partials -> kv[64][64], ksum[64].
// Pass 2: lean streaming loop: qp frags -> denom via ksum-broadcast MFMA,
//   num via kv MFMA, out = num * rcp(denom). No LDS/VALU-chains in loop.

#define NPTS 262144
#define TILES (NPTS / 64)      // 4096
#define GRID1 512
#define TPB1 (TILES / GRID1)   // 8
#define GRID2 1024
#define TPB2 (TILES / GRID2)   // 4
#define EPS 1e-3f

typedef __attribute__((ext_vector_type(8))) short short8;   // 8 x bf16 (4 VGPRs)
typedef __attribute__((ext_vector_type(4))) float f32x4;

__device__ __forceinline__ unsigned short f2bf(float f) {
    unsigned u = __builtin_bit_cast(unsigned, f);
    u += 0x7FFFu + ((u >> 16) & 1u);           // round-to-nearest-even
    return (unsigned short)(u >> 16);
}

__device__ __forceinline__ short8 cvt8(float4 p0, float4 p1) {
    short8 a;
    a[0] = (short)f2bf(p0.x); a[1] = (short)f2bf(p0.y); a[2] = (short)f2bf(p0.z); a[3] = (short)f2bf(p0.w);
    a[4] = (short)f2bf(p1.x); a[5] = (short)f2bf(p1.y); a[6] = (short)f2bf(p1.z); a[7] = (short)f2bf(p1.w);
    return a;
}

// barrier that drains LDS ops only (keeps global prefetch loads in flight)
__device__ __forceinline__ void lds_barrier() {
    asm volatile("s_waitcnt lgkmcnt(0)" ::: "memory");
    __builtin_amdgcn_s_barrier();
}

__global__ __launch_bounds__(256, 2) void pass1_kernel(
    const float* __restrict__ x,
    const float* __restrict__ Wq, const float* __restrict__ bq,
    const float* __restrict__ Wk, const float* __restrict__ bk,
    const float* __restrict__ Wv, const float* __restrict__ bv,
    float* __restrict__ kvPart, float* __restrict__ ksPart,
    unsigned short* __restrict__ qpW)
{
    __shared__ unsigned short kpT[64][72];       // kp transposed [m][n]; startup: W staging
    __shared__ unsigned short vT[64][72];        // v  transposed [d][n]
    __shared__ unsigned short qpT[64][72];       // qp transposed [m][n] (wave-private cols)
    __shared__ unsigned short wkF[8][64][8];     // B-frags: [j*2+kk][lane][e]
    __shared__ unsigned short wvF[8][64][8];
    __shared__ unsigned short wqF[8][64][8];

    const int tid = threadIdx.x;
    const int w = tid >> 6, l = tid & 63, l15 = l & 15, lg = l >> 4;

    // ---- startup: coalesced W staging (float4) -> LDS bf16 -> frag build ----
    {
        const float* Ws[3] = {Wk, Wv, Wq};
        unsigned short (*Fs[3])[64][8] = {wkF, wvF, wqF};
        const int srow = tid >> 2, sc0 = (tid & 3) * 16;
#pragma unroll
        for (int m = 0; m < 3; ++m) {
            const float* p = Ws[m] + srow * 64 + sc0;
            float4 f0 = ((const float4*)p)[0];
            float4 f1 = ((const float4*)p)[1];
            float4 f2 = ((const float4*)p)[2];
            float4 f3 = ((const float4*)p)[3];
            float ff[16] = {f0.x, f0.y, f0.z, f0.w, f1.x, f1.y, f1.z, f1.w,
                            f2.x, f2.y, f2.z, f2.w, f3.x, f3.y, f3.z, f3.w};
            unsigned hh[8];
#pragma unroll
            for (int e = 0; e < 8; ++e)
                hh[e] = (unsigned)f2bf(ff[2 * e]) | ((unsigned)f2bf(ff[2 * e + 1]) << 16);
            uint4 u0 = {hh[0], hh[1], hh[2], hh[3]};
            uint4 u1 = {hh[4], hh[5], hh[6], hh[7]};
            *(uint4*)&kpT[srow][sc0] = u0;
            *(uint4*)&kpT[srow][sc0 + 8] = u1;
            __syncthreads();
            // wave w builds frag j=w (both kk): F[j*2+kk][lane][e] = W[k=kk*32+lg*8+e][j*16+l15]
#pragma unroll
            for (int kk = 0; kk < 2; ++kk) {
                short8 t;
#pragma unroll
                for (int e = 0; e < 8; ++e)
                    t[e] = (short)kpT[kk * 32 + lg * 8 + e][w * 16 + l15];
                *(short8*)&Fs[m][w * 2 + kk][l][0] = t;
            }
            __syncthreads();
        }
    }
    float bkl[4], bvl[4], bql[4];
#pragma unroll
    for (int j = 0; j < 4; ++j) {
        bkl[j] = bk[j * 16 + l15]; bvl[j] = bv[j * 16 + l15]; bql[j] = bq[j * 16 + l15];
    }

    f32x4 akv[4];
#pragma unroll
    for (int j = 0; j < 4; ++j) akv[j] = (f32x4){0.f, 0.f, 0.f, 0.f};
    float ks[4] = {0.f, 0.f, 0.f, 0.f};

    const int t0 = blockIdx.x * TPB1;
    const float* xbase = x + ((size_t)t0 * 64 + w * 16 + l15) * 64 + lg * 8;
    float4 c0 = *(const float4*)(xbase + 0);
    float4 c1 = *(const float4*)(xbase + 4);
    float4 c2 = *(const float4*)(xbase + 32);
    float4 c3 = *(const float4*)(xbase + 36);
    const int nbase = w * 16 + lg * 4;

    for (int t = 0; t < TPB1; ++t) {
        // prefetch next tile (safe re-read of current on last iter)
        const float* xn = xbase + (size_t)((t + 1 < TPB1) ? (t + 1) : t) * 4096;
        float4 n0 = *(const float4*)(xn + 0);
        float4 n1 = *(const float4*)(xn + 4);
        float4 n2 = *(const float4*)(xn + 32);
        float4 n3 = *(const float4*)(xn + 36);

        short8 a0 = cvt8(c0, c1);
        short8 a1 = cvt8(c2, c3);

#pragma unroll
        for (int j = 0; j < 4; ++j) {
            short8 bk0 = *(const short8*)&wkF[j * 2 + 0][l][0];
            short8 bk1 = *(const short8*)&wkF[j * 2 + 1][l][0];
            short8 bv0 = *(const short8*)&wvF[j * 2 + 0][l][0];
            short8 bv1 = *(const short8*)&wvF[j * 2 + 1][l][0];
            short8 bq0 = *(const short8*)&wqF[j * 2 + 0][l][0];
            short8 bq1 = *(const short8*)&wqF[j * 2 + 1][l][0];
            f32x4 z = (f32x4){0.f, 0.f, 0.f, 0.f};
            f32x4 ak = __builtin_amdgcn_mfma_f32_16x16x32_bf16(a0, bk0, z, 0, 0, 0);
            ak = __builtin_amdgcn_mfma_f32_16x16x32_bf16(a1, bk1, ak, 0, 0, 0);
            f32x4 av = __builtin_amdgcn_mfma_f32_16x16x32_bf16(a0, bv0, z, 0, 0, 0);
            av = __builtin_amdgcn_mfma_f32_16x16x32_bf16(a1, bv1, av, 0, 0, 0);
            f32x4 aq = __builtin_amdgcn_mfma_f32_16x16x32_bf16(a0, bq0, z, 0, 0, 0);
            aq = __builtin_amdgcn_mfma_f32_16x16x32_bf16(a1, bq1, aq, 0, 0, 0);
            unsigned short h[4], g[4], q[4];
#pragma unroll
            for (int r = 0; r < 4; ++r) {
                float kp = fmaxf(ak[r] + bkl[j], 0.f) + EPS;
                ks[j] += kp;
                h[r] = f2bf(kp);
                g[r] = f2bf(av[r] + bvl[j]);
                q[r] = f2bf(fmaxf(aq[r] + bql[j], 0.f) + EPS);
            }
            uint2 hp = {(unsigned)h[0] | ((unsigned)h[1] << 16), (unsigned)h[2] | ((unsigned)h[3] << 16)};
            uint2 gp = {(unsigned)g[0] | ((unsigned)g[1] << 16), (unsigned)g[2] | ((unsigned)g[3] << 16)};
            uint2 qp2 = {(unsigned)q[0] | ((unsigned)q[1] << 16), (unsigned)q[2] | ((unsigned)q[3] << 16)};
            *(uint2*)&kpT[j * 16 + l15][nbase] = hp;
            *(uint2*)&vT[j * 16 + l15][nbase] = gp;
            *(uint2*)&qpT[j * 16 + l15][nbase] = qp2;
        }
        lds_barrier();
        // kv[m][d] += sum_n kp[n][m] * v[n][d]; wave w owns m in [w*16, w*16+16)
        short8 ka0 = *(const short8*)&kpT[w * 16 + l15][lg * 8];
        short8 ka1 = *(const short8*)&kpT[w * 16 + l15][32 + lg * 8];
#pragma unroll
        for (int j = 0; j < 4; ++j) {
            short8 vb0 = *(const short8*)&vT[j * 16 + l15][lg * 8];
            short8 vb1 = *(const short8*)&vT[j * 16 + l15][32 + lg * 8];
            akv[j] = __builtin_amdgcn_mfma_f32_16x16x32_bf16(ka0, vb0, akv[j], 0, 0, 0);
            akv[j] = __builtin_amdgcn_mfma_f32_16x16x32_bf16(ka1, vb1, akv[j], 0, 0, 0);
        }
        // qp export: row-major bf16, exactly pass2's A-frag load layout
        short8 q0, q1;
#pragma unroll
        for (int e = 0; e < 8; ++e) {
            q0[e] = (short)qpT[lg * 8 + e][w * 16 + l15];
            q1[e] = (short)qpT[32 + lg * 8 + e][w * 16 + l15];
        }
        unsigned short* qdst = qpW + ((size_t)(t0 + t) * 64 + w * 16 + l15) * 64 + lg * 8;
        *(short8*)(qdst) = q0;
        *(short8*)(qdst + 32) = q1;
        lds_barrier();
        c0 = n0; c1 = n1; c2 = n2; c3 = n3;
    }

    // per-block partial stores (plain, coalesced)
    float* kvs = kvPart + (size_t)blockIdx.x * 4096;
#pragma unroll
    for (int j = 0; j < 4; ++j)
#pragma unroll
        for (int r = 0; r < 4; ++r)
            kvs[(size_t)(w * 16 + lg * 4 + r) * 64 + j * 16 + l15] = akv[j][r];
#pragma unroll
    for (int j = 0; j < 4; ++j) {
        float s = ks[j];
        s += __shfl_xor(s, 16, 64);
        s += __shfl_xor(s, 32, 64);
        if (lg == 0) ksPart[(size_t)blockIdx.x * 256 + w * 64 + j * 16 + l15] = s;
    }
}

// 65 blocks: b<64 -> kv outputs b*64..b*64+63; b==64 -> ksum outputs 0..63
__global__ __launch_bounds__(256, 4) void reduce_kernel(
    const float* __restrict__ kvPart, const float* __restrict__ ksPart,
    float* __restrict__ kvFin, float* __restrict__ ksFin)
{
    __shared__ float red[4][64];
    const int b = blockIdx.x, t = threadIdx.x;
    const int oo = t & 63, sc = t >> 6;
    float acc = 0.f;
    if (b < 64) {
        const float* p = kvPart + (size_t)sc * 128 * 4096 + b * 64 + oo;
#pragma unroll 8
        for (int s = 0; s < GRID1 / 4; ++s) acc += p[(size_t)s * 4096];
    } else {
        const float* p = ksPart + (size_t)sc * GRID1 * 64 + oo;
#pragma unroll 8
        for (int s = 0; s < GRID1; ++s) acc += p[(size_t)s * 64];
    }
    red[sc][oo] = acc;
    __syncthreads();
    if (t < 64) {
        float s = red[0][t] + red[1][t] + red[2][t] + red[3][t];
        if (b < 64) kvFin[b * 64 + t] = s;
        else        ksFin[t] = s;
    }
}

__global__ __launch_bounds__(256, 4) void pass2_kernel(
    const unsigned short* __restrict__ qpW, const float* __restrict__ kvFin,
    const float* __restrict__ ksFin, float* __restrict__ out)
{
    __shared__ unsigned short kvS[64][72];   // startup staging only

    const int tid = threadIdx.x;
    const int w = tid >> 6, l = tid & 63, l15 = l & 15, lg = l >> 4;

    // stage kv (f32, coalesced) -> LDS bf16; build all 8 kv frags in registers
    {
        const int srow = tid >> 2, sc0 = (tid & 3) * 16;
        const float* p = kvFin + srow * 64 + sc0;
        float4 f0 = ((const float4*)p)[0];
        float4 f1 = ((const float4*)p)[1];
        float4 f2 = ((const float4*)p)[2];
        float4 f3 = ((const float4*)p)[3];
        float ff[16] = {f0.x, f0.y, f0.z, f0.w, f1.x, f1.y, f1.z, f1.w,
                        f2.x, f2.y, f2.z, f2.w, f3.x, f3.y, f3.z, f3.w};
        unsigned hh[8];
#pragma unroll
        for (int e = 0; e < 8; ++e)
            hh[e] = (unsigned)f2bf(ff[2 * e]) | ((unsigned)f2bf(ff[2 * e + 1]) << 16);
        uint4 u0 = {hh[0], hh[1], hh[2], hh[3]};
        uint4 u1 = {hh[4], hh[5], hh[6], hh[7]};
        *(uint4*)&kvS[srow][sc0] = u0;
        *(uint4*)&kvS[srow][sc0 + 8] = u1;
    }
    __syncthreads();
    short8 kvf[4][2];
#pragma unroll
    for (int j = 0; j < 4; ++j)
#pragma unroll
        for (int kk = 0; kk < 2; ++kk) {
            short8 t;
#pragma unroll
            for (int e = 0; e < 8; ++e)
                t[e] = (short)kvS[kk * 32 + lg * 8 + e][j * 16 + l15];
            kvf[j][kk] = t;
        }
    // ksum broadcast B-frags: B[k][*] = ksum[k] -> denom lands in every lane's C
    short8 ksf0, ksf1;
#pragma unroll
    for (int e = 0; e < 8; ++e) {
        ksf0[e] = (short)f2bf(ksFin[lg * 8 + e]);
        ksf1[e] = (short)f2bf(ksFin[32 + lg * 8 + e]);
    }

    const int t0 = blockIdx.x * TPB2;
    const unsigned short* qbase = qpW + ((size_t)t0 * 64 + w * 16 + l15) * 64 + lg * 8;
    short8 an0 = *(const short8*)(qbase);
    short8 an1 = *(const short8*)(qbase + 32);

#pragma unroll
    for (int t = 0; t < TPB2; ++t) {
        const unsigned short* qn = qbase + (size_t)((t + 1 < TPB2) ? (t + 1) : t) * 4096;
        short8 m0 = *(const short8*)(qn);
        short8 m1 = *(const short8*)(qn + 32);

        f32x4 z = (f32x4){0.f, 0.f, 0.f, 0.f};
        f32x4 dn = __builtin_amdgcn_mfma_f32_16x16x32_bf16(an0, ksf0, z, 0, 0, 0);
        dn = __builtin_amdgcn_mfma_f32_16x16x32_bf16(an1, ksf1, dn, 0, 0, 0);
        float inv[4];
#pragma unroll
        for (int r = 0; r < 4; ++r) inv[r] = __builtin_amdgcn_rcpf(dn[r]);

        const size_t row0 = (size_t)(t0 + t) * 64 + w * 16;
#pragma unroll
        for (int j = 0; j < 4; ++j) {
            f32x4 nm = __builtin_amdgcn_mfma_f32_16x16x32_bf16(an0, kvf[j][0], z, 0, 0, 0);
            nm = __builtin_amdgcn_mfma_f32_16x16x32_bf16(an1, kvf[j][1], nm, 0, 0, 0);
#pragma unroll
            for (int r = 0; r < 4; ++r)
                out[(row0 + lg * 4 + r) * 64 + j * 16 + l15] = nm[r] * inv[r];
        }
        an0 = m0; an1 = m1;
    }
}

extern "C" void kernel_launch(void* const* d_in, const int* in_sizes, int n_in,
                              void* d_out, int out_size, void* d_ws, size_t ws_size,
                              hipStream_t stream)
{
    const float* x  = (const float*)d_in[0];
    const float* Wq = (const float*)d_in[1];
    const float* bq = (const float*)d_in[2];
    const float* Wk = (const float*)d_in[3];
    const float* bk = (const float*)d_in[4];
    const float* Wv = (const float*)d_in[5];
    const float* bv = (const float*)d_in[6];
    float* out = (float*)d_out;

    float* kvPart = (float*)d_ws;                              // [512][4096] f32
    float* ksPart = kvPart + (size_t)GRID1 * 4096;             // [512][256] f32
    float* kvFin  = ksPart + (size_t)GRID1 * 256;              // [4096] f32
    float* ksFin  = kvFin + 4096;                              // [64] f32
    unsigned short* qpW = (unsigned short*)(ksFin + 64);       // [N][64] bf16, 16B-aligned

    hipLaunchKernelGGL(pass1_kernel, dim3(GRID1), dim3(256), 0, stream,
                       x, Wq, bq, Wk, bk, Wv, bv, kvPart, ksPart, qpW);
    hipLaunchKernelGGL(reduce_kernel, dim3(65), dim3(256), 0, stream,
                       kvPart, ksPart, kvFin, ksFin);
    hipLaunchKernelGGL(pass2_kernel, dim3(GRID2), dim3(256), 0, stream,
                       qpW, kvFin, ksFin, out);
}